// Round 11
// baseline (168131.213 us; speedup 1.0000x reference)
//
#include <hip/hip_runtime.h>
#include <hip/hip_bf16.h>

#define HD 2048      // hidden size
#define TT 8192      // time steps
#define RPB 16       // rows per block
#define NTHR 512     // threads per block
#define SENTU 0xAAAAAAAAu

// Fused 2-layer Elman RNN, one 256-block kernel (1 block/CU), REGISTER-DIRECT:
// no LDS h-staging, no per-step barriers. Each thread polls its own 64 h-words
// (32 pair-atomics) straight into FMA input registers. Waves free-run.
// Blocks [0,128): layer 0.   h1_{s+1} = tanh(x[s]*wih0 + b + Whh0 h1_s)
// Blocks [128,256): layer 1. h2_{s+1} = tanh(Wih1 h1_{s+1} + b + Whh1 h2_s)
//   l1 splits each step: (A) consume upstream h1_{s+1} (arrives ~1 hop early,
//   off the recurrent path -> usually zero wait), (B) poll own h2_s (critical).
// Sync: dataflow polling on once-written 8B slot pairs, sentinel 0xAAAAAAAA
// from our own memset; agent-scope atomics (coherence point valid x-XCD).

typedef unsigned long long ull;

__device__ __forceinline__ unsigned fix_sent_u(float v) {
    unsigned u = __float_as_uint(v);
    return (u == SENTU) ? 0xAAAAAABAu : u;   // 2^-13 rel nudge; prob ~0
}
__device__ __forceinline__ void slot_store_pair(ull* p, float lo, float hi) {
    ull v = (ull)fix_sent_u(lo) | ((ull)fix_sent_u(hi) << 32);
    __hip_atomic_store(p, v, __ATOMIC_RELAXED, __HIP_MEMORY_SCOPE_AGENT);
}
__device__ __forceinline__ ull slot_load64(const ull* p) {
    return __hip_atomic_load(p, __ATOMIC_RELAXED, __HIP_MEMORY_SCOPE_AGENT);
}
__device__ __forceinline__ bool pair_ok(ull t) {
    return ((unsigned)t != SENTU) && ((unsigned)(t >> 32) != SENTU);
}

// Poll one 64-word range (32 pairs) into hv[64] (statically indexed -> VGPRs).
// Doubly bounded (pass cap + global budget) -> fast wrong answer, never a wedge.
__device__ __forceinline__ void poll64(const ull* p, float* hv, long& gb) {
    unsigned got = 0;
    int passes = 1024;
    for (;;) {
        #pragma unroll
        for (int j = 0; j < 32; ++j) {
            if (!(got & (1u << j))) {
                ull t = slot_load64(p + j);
                if (pair_ok(t)) {
                    hv[2*j]   = __uint_as_float((unsigned)t);
                    hv[2*j+1] = __uint_as_float((unsigned)(t >> 32));
                    got |= (1u << j);
                }
            }
        }
        if (got == 0xFFFFFFFFu) return;
        if (--passes < 0 || --gb < 0) {
            #pragma unroll
            for (int j = 0; j < 32; ++j)
                if (!(got & (1u << j))) { hv[2*j] = 0.f; hv[2*j+1] = 0.f; }
            return;
        }
        if (passes < 1016) __builtin_amdgcn_s_sleep(1);   // backoff after 8 tight passes
    }
}

__global__ __launch_bounds__(NTHR, 2)   // 2 waves/EU -> 1 block/CU, <=256 VGPR
void rnn_fused(const float* __restrict__ x,
               const float* __restrict__ h_init,    // (2,1,HD)
               const float* __restrict__ Wih0,      // (HD,1)
               const float* __restrict__ Whh0,      // (HD,HD)
               const float* __restrict__ bih0,
               const float* __restrict__ bhh0,
               const float* __restrict__ Wih1,      // (HD,HD)
               const float* __restrict__ Whh1,      // (HD,HD)
               const float* __restrict__ bih1,
               const float* __restrict__ bhh1,
               float* __restrict__ slots0,          // (TT+1) x HD
               float* __restrict__ slots1,          // (TT+1) x HD
               float* __restrict__ out)             // (2,1,HD) flat
{
    __shared__ float xs[TT];           // 32 KB, layer-0 input sequence (read-only)

    const int tid = threadIdx.x;
    const int bid = blockIdx.x;
    const bool is_l0 = (bid < 128);
    const int blk = is_l0 ? bid : (bid - 128);
    const int r   = tid >> 5;          // 0..15: row within block
    const int l   = tid & 31;          // k-slice lane: words [l*64, l*64+64)
    const int fl  = tid & 63;          // lane in physical wave
    const int wid = tid >> 6;          // physical wave 0..7 (publishes rows 2w,2w+1)
    const int row = blk * RPB + r;

    // pair index this wave publishes (rows {2wid, 2wid+1}) within a step's 1024 pairs
    const size_t mypair = (size_t)blk * (RPB/2) + wid;
    // pair index this thread polls: words [l*64 .. l*64+64) -> pairs [l*32 ..)
    const int rdpair = l * 32;

    float lastv = 0.f;
    long  gbudget = 1L << 20;   // worst-case total spin ~0.25 s -> fast wrong answer

    if (is_l0) {
        for (int i = tid; i < TT; i += NTHR) xs[i] = x[i];

        float w[64];
        {
            const float4* wr = reinterpret_cast<const float4*>(Whh0 + (size_t)row * HD + l * 64);
            #pragma unroll
            for (int j = 0; j < 16; ++j) {
                float4 v = wr[j];
                w[4*j+0] = v.x; w[4*j+1] = v.y; w[4*j+2] = v.z; w[4*j+3] = v.w;
            }
        }
        const float wx   = Wih0[row];
        const float bias = bih0[row] + bhh0[row];

        __syncthreads();   // xs ready (only barrier in the kernel)

        { // publish initial h1 (slot 0) as pairs
            float v0 = h_init[row];
            float v1 = __shfl_xor(v0, 32);
            if (fl == 0)
                slot_store_pair(reinterpret_cast<ull*>(slots0) + mypair, v0, v1);
        }

        for (int s = 0; s < TT; ++s) {
            float hv[64];
            poll64(reinterpret_cast<const ull*>(slots0 + (size_t)s * HD) + rdpair, hv, gbudget);

            float acc = 0.f;
            #pragma unroll
            for (int k = 0; k < 64; ++k) acc = fmaf(w[k], hv[k], acc);
            #pragma unroll
            for (int m = 1; m < 32; m <<= 1) acc += __shfl_xor(acc, m);

            float val = tanhf(acc + bias + xs[s] * wx);   // valid on ALL lanes
            lastv = val;
            float v1 = __shfl_xor(val, 32);               // partner row's value
            if (fl == 0)
                slot_store_pair(reinterpret_cast<ull*>(slots0 + (size_t)(s + 1) * HD) + mypair,
                                val, v1);
        }
        if (l == 0) out[row] = lastv;
    } else {
        float wh[64], wi[64];
        {
            const float4* a = reinterpret_cast<const float4*>(Whh1 + (size_t)row * HD + l * 64);
            const float4* b = reinterpret_cast<const float4*>(Wih1 + (size_t)row * HD + l * 64);
            #pragma unroll
            for (int j = 0; j < 16; ++j) {
                float4 v = a[j];
                wh[4*j+0] = v.x; wh[4*j+1] = v.y; wh[4*j+2] = v.z; wh[4*j+3] = v.w;
                float4 u = b[j];
                wi[4*j+0] = u.x; wi[4*j+1] = u.y; wi[4*j+2] = u.z; wi[4*j+3] = u.w;
            }
        }
        const float bias = bih1[row] + bhh1[row];

        { // publish initial h2 (slot 0)
            float v0 = h_init[HD + row];
            float v1 = __shfl_xor(v0, 32);
            if (fl == 0)
                slot_store_pair(reinterpret_cast<ull*>(slots1) + mypair, v0, v1);
        }

        for (int s = 0; s < TT; ++s) {
            float hv[64];   // reused across both phases -> keeps VGPRs ~210

            // phase A (off recurrent path): upstream h1_{s+1}; usually already present
            poll64(reinterpret_cast<const ull*>(slots0 + (size_t)(s + 1) * HD) + rdpair, hv, gbudget);
            float acc = 0.f;
            #pragma unroll
            for (int k = 0; k < 64; ++k) acc = fmaf(wi[k], hv[k], acc);

            // phase B (critical): own h2_s
            poll64(reinterpret_cast<const ull*>(slots1 + (size_t)s * HD) + rdpair, hv, gbudget);
            #pragma unroll
            for (int k = 0; k < 64; ++k) acc = fmaf(wh[k], hv[k], acc);

            #pragma unroll
            for (int m = 1; m < 32; m <<= 1) acc += __shfl_xor(acc, m);

            float val = tanhf(acc + bias);
            lastv = val;
            float v1 = __shfl_xor(val, 32);
            if (fl == 0)
                slot_store_pair(reinterpret_cast<ull*>(slots1 + (size_t)(s + 1) * HD) + mypair,
                                val, v1);
        }
        if (l == 0) out[HD + row] = lastv;
    }
}

extern "C" void kernel_launch(void* const* d_in, const int* in_sizes, int n_in,
                              void* d_out, int out_size, void* d_ws, size_t ws_size,
                              hipStream_t stream)
{
    const float* x    = (const float*)d_in[0];
    const float* h    = (const float*)d_in[1];   // (2,1,H)
    const float* Wih0 = (const float*)d_in[2];
    const float* Whh0 = (const float*)d_in[3];
    const float* bih0 = (const float*)d_in[4];
    const float* bhh0 = (const float*)d_in[5];
    const float* Wih1 = (const float*)d_in[6];
    const float* Whh1 = (const float*)d_in[7];
    const float* bih1 = (const float*)d_in[8];
    const float* bhh1 = (const float*)d_in[9];
    float* out = (float*)d_out;

    float* slots0 = (float*)d_ws;
    float* slots1 = slots0 + (size_t)(TT + 1) * HD;
    size_t need = (size_t)2 * (TT + 1) * HD * sizeof(float);
    if (ws_size < need) return;

    // sentinel-fill both slot regions (self-contained; don't rely on harness poison)
    hipMemsetAsync(d_ws, 0xAA, need, stream);

    hipLaunchKernelGGL(rnn_fused, dim3(256), dim3(NTHR), 0, stream,
                       x, h, Wih0, Whh0, bih0, bhh0, Wih1, Whh1, bih1, bhh1,
                       slots0, slots1, out);
}